// Round 12
// baseline (92.054 us; speedup 1.0000x reference)
//
#include <hip/hip_runtime.h>
#include <hip/hip_bf16.h>

#define BATCH 4096
#define NROWS 8192
#define DIM   128
#define NTILE 64

typedef __bf16 bf16x8 __attribute__((ext_vector_type(8)));
typedef __bf16 bf16x2 __attribute__((ext_vector_type(2)));
typedef float  f32x4  __attribute__((ext_vector_type(4)));

// ---------------------------------------------------------------------------
// Kernel 1: row-normalize z = concat(zx, zy) -> bf16 zn [8192 x 128].
// One wave per row. Zeroes S (blocks 0..31) and out (block 0) so later
// dispatches accumulate into poisoned workspace with no memset dispatches.
// ---------------------------------------------------------------------------
__global__ __launch_bounds__(256) void normalize_kernel(
    const float* __restrict__ zx, const float* __restrict__ zy,
    ushort* __restrict__ zn, float* __restrict__ S, float* __restrict__ out)
{
  const int tid  = threadIdx.x;
  const int lane = tid & 63;
  const int w    = tid >> 6;
  const int row  = blockIdx.x * 4 + w;
  if (blockIdx.x < 32) S[blockIdx.x * 256 + tid] = 0.f;
  if (blockIdx.x == 0 && tid == 0) out[0] = 0.f;
  const float* src = (row < BATCH) ? (zx + (size_t)row * DIM)
                                   : (zy + (size_t)(row - BATCH) * DIM);
  float2 v = ((const float2*)src)[lane];
  float ss = v.x * v.x + v.y * v.y;
#pragma unroll
  for (int off = 1; off < 64; off <<= 1)
    ss += __shfl_xor(ss, off, 64);
  float inv = 1.0f / fmaxf(sqrtf(ss), 1e-8f);
  bf16x2 st;
  st.x = (__bf16)(v.x * inv);
  st.y = (__bf16)(v.y * inv);
  reinterpret_cast<bf16x2*>(zn + (size_t)row * DIM)[lane] = st;
}

// ---------------------------------------------------------------------------
// Kernel 2 (v11): v5's decomposition, LDS-FREE and BARRIER-FREE, no spill.
// Every staged variant (v5/v6/v10) pinned at ~25-30us with all pipes <10%
// busy: the per-tile stage -> vmcnt(0)-drain -> barrier -> ds_read chain in
// wave-lockstep is the shared suspect. LDS staging is pointless here anyway:
// within a block both wr-waves read IDENTICAL B rows (row = f(wc,ni,l15)),
// so the per-tile working set is 2 x 16 KiB = L1-sized, and zn (2 MiB) is
// L2-resident. v11 loads B-fragments straight from zn; waves are fully
// independent; the compiler pipelines the 16 independent per-tile loads
// under MFMA with counted vmcnt.
// v7 tried this but launch_bounds(256,3) capped VGPR at 168 -> ~80 MB
// scratch spill (FETCH/WRITE 39/41 MB). Here launch_bounds(256,2): cap 256,
// need ~190 -> no spill (falsifier: FETCH/WRITE must stay ~10-20/4 MB).
//
// Decomposition (v5, proven): lower triangle as 32 row-pairs {p,63-p} of 65
// tiles, 16 chunks -> 512 blocks; chunk 0: 5 tiles, rest 4 (<=1 A-reload).
// Row/col sums -> S[8192] via shfl-reduce + atomicAdd (S pre-zeroed; proven
// faster than plain-store slots in r10). Positive-pair tiles (rb-cb==32)
// write P[i] and mirror P[i-4096].
// ---------------------------------------------------------------------------
__global__ __launch_bounds__(256, 2) void simloss_kernel(
    const ushort* __restrict__ zn, float* __restrict__ S,
    float* __restrict__ P)
{
  const int tid  = threadIdx.x;
  const int lane = tid & 63;
  const int w    = tid >> 6;       // wave 0..3
  const int wr   = w >> 1, wc = w & 1;
  const int q    = lane >> 4;      // quad 0..3
  const int l15  = lane & 15;

  const int p  = blockIdx.x >> 4;            // pair 0..31: rows {p, 63-p}
  const int ch = blockIdx.x & 15;            // chunk 0..15
  const int o0 = (ch == 0) ? 0 : 1 + ch * 4; // seq start: 0,5,9,...,61
  const int T  = (ch == 0) ? 5 : 4;          // tiles in this chunk
  const int L0 = p + 1;                      // tiles in short row (rb = p)

  auto tile_rc = [&](int o, int& rb, int& cb) {
    if (o < L0) { rb = p;      cb = o; }
    else        { rb = 63 - p; cb = o - L0; }
  };

  // A fragments: rows rb*128 + wr*64 + mi*16 + l15, k chunk q*8 within ks*32
  bf16x8 af[4][4];
  auto loadA = [&](int rb) {
    const int arow = rb * 128 + wr * 64 + l15;
#pragma unroll
    for (int mi = 0; mi < 4; ++mi)
#pragma unroll
      for (int ks = 0; ks < 4; ++ks) {
        const ushort* ap = zn + (size_t)(arow + mi * 16) * DIM + ks * 32 + q * 8;
        af[mi][ks] = *reinterpret_cast<const bf16x8*>(ap);
      }
  };

  int rb0, cb0;
  tile_rc(o0, rb0, cb0);
  loadA(rb0);

  f32x4 Srow[4];       // per mi, elems r=0..3, accumulated across the row run
#pragma unroll
  for (int mi = 0; mi < 4; ++mi) Srow[mi] = (f32x4){0.f, 0.f, 0.f, 0.f};

  const float K1 = 2.8853900817779268f;  // (1/TEMP) * log2(e)

  for (int t = 0; t < T; ++t) {
    const int o = o0 + t;
    int trb, tcb;
    tile_rc(o, trb, tcb);
    int nrb = -1, ncb = -1;
    if (t + 1 < T) tile_rc(o + 1, nrb, ncb);

    f32x4 acc[4][4];
#pragma unroll
    for (int mi = 0; mi < 4; ++mi)
#pragma unroll
      for (int ni = 0; ni < 4; ++ni)
        acc[mi][ni] = (f32x4){0.f, 0.f, 0.f, 0.f};

    // B-fragments straight from zn (L1/L2-resident): row nl of col-block
    // tcb; both wr-waves read the same rows -> L1 reuse. 16 independent
    // 16B loads per tile, pipelined under MFMA by the compiler.
    const ushort* bbase = zn + (size_t)(tcb * 128) * DIM;
#pragma unroll
    for (int ks = 0; ks < 4; ++ks) {
      bf16x8 bf[4];
#pragma unroll
      for (int ni = 0; ni < 4; ++ni) {
        const int nl = wc * 64 + ni * 16 + l15;   // B row in tile (sim col)
        bf[ni] = *reinterpret_cast<const bf16x8*>(
            bbase + (size_t)nl * DIM + ks * 32 + q * 8);
      }
#pragma unroll
      for (int mi = 0; mi < 4; ++mi)
#pragma unroll
        for (int ni = 0; ni < 4; ++ni)
          acc[mi][ni] = __builtin_amdgcn_mfma_f32_16x16x32_bf16(
              af[mi][ks], bf[ni], acc[mi][ni], 0, 0, 0);
    }

    // Epilogue: v = exp(sim-2) = exp2(K1*dot - K1).
    const bool diag = (trb == tcb);
    float Scol[4];
#pragma unroll
    for (int ni = 0; ni < 4; ++ni) Scol[ni] = 0.f;

#pragma unroll
    for (int mi = 0; mi < 4; ++mi)
#pragma unroll
      for (int ni = 0; ni < 4; ++ni) {
        f32x4 vv;
#pragma unroll
        for (int r = 0; r < 4; ++r) {
          float d = acc[mi][ni][r];
          float v = __builtin_amdgcn_exp2f(fmaf(d, K1, -K1));
          if (diag) {
            const int rl = wr * 64 + mi * 16 + q * 4 + r;
            const int cl = wc * 64 + ni * 16 + l15;
            if (rl == cl) v = 0.f;
          }
          vv[r] = v;
        }
        Srow[mi] += vv;
        Scol[ni] += (vv[0] + vv[1]) + (vv[2] + vv[3]);
      }

    // Positive pairs: tile (rb, rb-32) has sim[i, i-4096] at local rl==cl.
    if (trb - tcb == 32) {
#pragma unroll
      for (int mi = 0; mi < 4; ++mi) {
        const int rl0 = wr * 64 + mi * 16 + q * 4;
#pragma unroll
        for (int ni = 0; ni < 4; ++ni) {
          const int cl = wc * 64 + ni * 16 + l15;
#pragma unroll
          for (int r = 0; r < 4; ++r) {
            if (cl == rl0 + r) {
              const int gr = trb * 128 + rl0 + r;
              const float pv = 2.0f * acc[mi][ni][r];
              P[gr] = pv;
              P[gr - 4096] = pv;   // symmetric partner
            }
          }
        }
      }
    }

    // Col-side flush (non-diag): reduce over quads; 16 lanes atomicAdd.
    if (!diag) {
#pragma unroll
      for (int ni = 0; ni < 4; ++ni) {
        float v = Scol[ni];
        v += __shfl_xor(v, 16, 64);
        v += __shfl_xor(v, 32, 64);
        if (lane < 16)
          atomicAdd(&S[tcb * 128 + wc * 64 + ni * 16 + l15], v);
      }
    }

    // Row-side flush at row switch or block end.
    const bool flushR = (t == T - 1) || (nrb != trb);
    if (flushR) {
#pragma unroll
      for (int mi = 0; mi < 4; ++mi)
#pragma unroll
        for (int r = 0; r < 4; ++r) {
          float v = Srow[mi][r];
          v += __shfl_xor(v, 1, 64);
          v += __shfl_xor(v, 2, 64);
          v += __shfl_xor(v, 4, 64);
          v += __shfl_xor(v, 8, 64);
          if (l15 == 0)
            atomicAdd(&S[trb * 128 + wr * 64 + mi * 16 + q * 4 + r], v);
        }
#pragma unroll
      for (int mi = 0; mi < 4; ++mi) Srow[mi] = (f32x4){0.f, 0.f, 0.f, 0.f};
      if (t + 1 < T && nrb != trb) loadA(nrb);  // one-time A reload
    }
  }
}

// ---------------------------------------------------------------------------
// Kernel 3: loss = mean_i( 2 + log(S_i) - P_i ); out zeroed by normalize.
// ---------------------------------------------------------------------------
__global__ __launch_bounds__(256) void finalize_kernel(
    const float* __restrict__ S, const float* __restrict__ P,
    float* __restrict__ out)
{
  const int i = blockIdx.x * 256 + threadIdx.x;
  float c = 2.0f + logf(S[i]) - P[i];
#pragma unroll
  for (int off = 1; off < 64; off <<= 1)
    c += __shfl_xor(c, off, 64);
  __shared__ float wsum[4];
  const int lane = threadIdx.x & 63, w = threadIdx.x >> 6;
  if (lane == 0) wsum[w] = c;
  __syncthreads();
  if (threadIdx.x == 0)
    atomicAdd(out, (wsum[0] + wsum[1] + wsum[2] + wsum[3]) * (1.0f / NROWS));
}

// ---------------------------------------------------------------------------
extern "C" void kernel_launch(void* const* d_in, const int* in_sizes, int n_in,
                              void* d_out, int out_size, void* d_ws, size_t ws_size,
                              hipStream_t stream)
{
  const float* zx = (const float*)d_in[0];
  const float* zy = (const float*)d_in[1];
  ushort* zn = (ushort*)d_ws;                                      // 2 MiB bf16
  float*  P  = (float*)((char*)d_ws + (size_t)NROWS * DIM * 2);    // 32 KiB
  float*  S  = P + NROWS;                                          // 32 KiB
  float*  out = (float*)d_out;

  normalize_kernel<<<NROWS / 4, 256, 0, stream>>>(zx, zy, zn, S, out);
  simloss_kernel<<<512, 256, 0, stream>>>(zn, S, P);
  finalize_kernel<<<NROWS / 256, 256, 0, stream>>>(S, P, out);
}